// Round 1
// baseline (1584.221 us; speedup 1.0000x reference)
//
#include <hip/hip_runtime.h>
#include <cstdint>
#include <cstddef>

#define T_ 512
#define B_ 32
#define E_ 256
#define NLAB 16

typedef __attribute__((ext_vector_type(8))) short short8;
typedef __attribute__((ext_vector_type(4))) float f32x4;
typedef __attribute__((ext_vector_type(16))) float f32x16;

// f32 -> bf16 round-to-nearest-even
static __device__ __forceinline__ unsigned short f2bf(float f) {
    unsigned u = __float_as_uint(f);
    u = (u + 0x7fffu + ((u >> 16) & 1u)) >> 16;
    return (unsigned short)u;
}

// B-fragment gather from f32 row-major [E][E] matrix, converted to bf16.
// v_mfma_f32_32x32x16_bf16 B layout (assumed): lane l holds B[k=8*(l>>5)+j][n=l&31], j=0..7
static __device__ __forceinline__ short8 gather_bfrag_f32(const float* Wt, int kt, int nt, int lane) {
    const float* p = Wt + (size_t)(kt * 16 + 8 * (lane >> 5)) * E_ + nt * 32 + (lane & 31);
    short8 r;
#pragma unroll
    for (int j = 0; j < 8; ++j) {
        float v = __builtin_nontemporal_load(p);
        r[j] = (short)f2bf(v);
        p += E_;
    }
    return r;
}

// A-fragment from per-lane row base pointer (f32): lane l holds A[m=l&31][k=8*(l>>5)+j]
static __device__ __forceinline__ short8 gather_afrag_rows(const float* rowbase, int kt, int lane) {
    const float* p = rowbase + kt * 16 + 8 * (lane >> 5);
    f32x4 v0 = *(const f32x4*)p;
    f32x4 v1 = *(const f32x4*)(p + 4);
    short8 r;
#pragma unroll
    for (int j = 0; j < 4; ++j) r[j] = (short)f2bf(v0[j]);
#pragma unroll
    for (int j = 0; j < 4; ++j) r[4 + j] = (short)f2bf(v1[j]);
    return r;
}

// A-fragment read from swizzled bf16 LDS c_buf[32][256]
static __device__ __forceinline__ short8 lds_afrag(const unsigned short* c_buf, int kt, int lane) {
    int b = lane & 31;
    int byte = (b * 512 + (kt * 16 + 8 * (lane >> 5)) * 2) ^ ((b & 7) << 4);
    return *(const short8*)((const char*)c_buf + byte);
}

// ---------------- Phase A2: z[d][t] = e_prev[d][t] @ Ws[d][t], stored in MFMA C/D lane order
__global__ void __launch_bounds__(512) zcompute_kernel(
        const int* __restrict__ inputs, const float* __restrict__ emb,
        const float* __restrict__ Wsl, const float* __restrict__ Wsr,
        const float* __restrict__ e_prev0, const float* __restrict__ e_foll0,
        float* __restrict__ z_out) {
    int bid = blockIdx.x;
    int d = bid >> 9, t = bid & 511;
    int tid = threadIdx.x, lane = tid & 63, w = tid >> 6;  // w = nt in 0..7
    const float* Ws = (d ? Wsr : Wsl) + (size_t)t * E_ * E_;
    int b = lane & 31;
    const float* rowbase;
    if (t == 0) {
        rowbase = (d ? e_foll0 : e_prev0) + b * E_;
    } else {
        int tok = inputs[b * T_ + (d ? (T_ - t) : (t - 1))];
        rowbase = emb + (size_t)tok * E_;
    }
    f32x16 acc;
#pragma unroll
    for (int r = 0; r < 16; ++r) acc[r] = 0.0f;
#pragma unroll 2
    for (int kt = 0; kt < 16; ++kt) {
        short8 a = gather_afrag_rows(rowbase, kt, lane);
        short8 bf = gather_bfrag_f32(Ws, kt, w, lane);
        acc = __builtin_amdgcn_mfma_f32_32x32x16_bf16(a, bf, acc, 0, 0, 0);
    }
    float* zp = z_out + (((size_t)(d * T_ + t) * 8 + w) * 64 + lane) * 16;
#pragma unroll
    for (int r = 0; r < 16; ++r) zp[r] = acc[r];
}

// ---------------- Phase A1: pack Wl/Wr into bf16 B-fragment order
__global__ void __launch_bounds__(512) wpack_kernel(
        const float* __restrict__ Wl, const float* __restrict__ Wr,
        unsigned short* __restrict__ wfrag) {
    int bid = blockIdx.x;
    int d = bid >> 9, t = bid & 511;
    int tid = threadIdx.x, lane = tid & 63, w = tid >> 6;  // nt
    const float* W = (d ? Wr : Wl) + (size_t)t * E_ * E_;
    unsigned short* dst = wfrag + (((size_t)(d * T_ + t) * 8 + w) * 16) * 512 + lane * 8;
#pragma unroll 2
    for (int kt = 0; kt < 16; ++kt) {
        short8 bf = gather_bfrag_f32(W, kt, w, lane);
        *(short8*)(dst + (size_t)kt * 512) = bf;
    }
}

// ---------------- Chain: one block per direction, 8 waves (wave = nt), c in LDS between steps
template <int MODE>  // 0 = FULL (wfrag + z precomputed), 1 = LITE (gather f32 inline)
__global__ void __launch_bounds__(512) chain_kernel(
        const int* __restrict__ inputs, const float* __restrict__ emb,
        const float* __restrict__ Wl, const float* __restrict__ Wsl,
        const float* __restrict__ Wr, const float* __restrict__ Wsr,
        const float* __restrict__ e_prev0, const float* __restrict__ e_foll0,
        const unsigned short* __restrict__ wfrag, const float* __restrict__ z_frag,
        float* __restrict__ pmax_out) {
    __shared__ unsigned short c_buf[32 * 256 + 32];  // bf16, XOR-swizzled
    int d = blockIdx.x;
    int tid = threadIdx.x, lane = tid & 63, w = tid >> 6;  // w = nt in 0..7
    const float* Wc = (d ? Wr : Wl);
    const float* Wsc = (d ? Wsr : Wsl);
    const float* e0 = (d ? e_foll0 : e_prev0);
    f32x16 lmax;
#pragma unroll
    for (int r = 0; r < 16; ++r) lmax[r] = -1e30f;

    for (int t = 0; t < T_; ++t) {
        f32x16 acc;
        if (MODE == 0) {
            const float* zp = z_frag + (((size_t)(d * T_ + t) * 8 + w) * 64 + lane) * 16;
#pragma unroll
            for (int r = 0; r < 16; ++r) acc[r] = zp[r];
        } else {
#pragma unroll
            for (int r = 0; r < 16; ++r) acc[r] = 0.0f;
            int b = lane & 31;
            const float* rowbase;
            if (t == 0) {
                rowbase = e0 + b * E_;
            } else {
                int tok = inputs[b * T_ + (d ? (T_ - t) : (t - 1))];
                rowbase = emb + (size_t)tok * E_;
            }
            const float* Ws = Wsc + (size_t)t * E_ * E_;
#pragma unroll 2
            for (int kt = 0; kt < 16; ++kt) {
                short8 a = gather_afrag_rows(rowbase, kt, lane);
                short8 bf = gather_bfrag_f32(Ws, kt, w, lane);
                acc = __builtin_amdgcn_mfma_f32_32x32x16_bf16(a, bf, acc, 0, 0, 0);
            }
        }

        if (t > 0) {
            // prefetch all B-fragments for this step into registers (no LDS dependence)
            short8 bf[16];
            if (MODE == 0) {
                const unsigned short* fb =
                    wfrag + (((size_t)(d * T_ + t) * 8 + w) * 16) * 512 + lane * 8;
#pragma unroll
                for (int kt = 0; kt < 16; ++kt) bf[kt] = *(const short8*)(fb + (size_t)kt * 512);
            } else {
                const float* Wt = Wc + (size_t)t * E_ * E_;
#pragma unroll 2
                for (int kt = 0; kt < 16; ++kt) bf[kt] = gather_bfrag_f32(Wt, kt, w, lane);
            }
            __syncthreads();  // c_buf from t-1 fully written
#pragma unroll
            for (int kt = 0; kt < 16; ++kt) {
                short8 a = lds_afrag(c_buf, kt, lane);
                acc = __builtin_amdgcn_mfma_f32_32x32x16_bf16(a, bf[kt], acc, 0, 0, 0);
            }
        }

        // tanh + running max
#pragma unroll
        for (int r = 0; r < 16; ++r) {
            float x = acc[r];
            float u = __expf(-2.0f * fabsf(x));
            float tv = (1.0f - u) / (1.0f + u);
            tv = copysignf(tv, x);
            acc[r] = tv;
            lmax[r] = fmaxf(lmax[r], tv);
        }

        __syncthreads();  // everyone done reading old c_buf
        {
            int n = w * 32 + (lane & 31);
#pragma unroll
            for (int r = 0; r < 16; ++r) {
                int b = (r & 3) + 8 * (r >> 2) + 4 * (lane >> 5);
                int byte = (b * 512 + n * 2) ^ ((b & 7) << 4);
                *(unsigned short*)((char*)c_buf + byte) = f2bf(acc[r]);
            }
        }
    }

    float* pm = pmax_out + (((size_t)d * 8 + w) * 64 + lane) * 16;
#pragma unroll
    for (int r = 0; r < 16; ++r) pm[r] = lmax[r];
}

// ---------------- Finalize: emb max-pool + assemble pooled + FC
__global__ void __launch_bounds__(256) finalize_kernel(
        const int* __restrict__ inputs, const float* __restrict__ emb,
        const float* __restrict__ pmax, const float* __restrict__ fc_w,
        const float* __restrict__ fc_b, float* __restrict__ out) {
    __shared__ float pooled[3 * E_];
    __shared__ float partial[NLAB][17];
    int b = blockIdx.x, e = threadIdx.x;

    // middle: max over t of emb_table[inputs[b][t]][e]
    float m = -1e30f;
    const int* tr = inputs + b * T_;
#pragma unroll 4
    for (int t = 0; t < T_; ++t) {
        int tok = tr[t];
        m = fmaxf(m, emb[(size_t)tok * E_ + e]);
    }
    pooled[E_ + e] = m;

    // left/right from pmax: invert C/D mapping row=(r&3)+8*(r>>2)+4*h, col=n
    int h = (b >> 2) & 1;
    int r = (b & 3) + 4 * (b >> 3);
    int nt = e >> 5, ln = (e & 31) + 32 * h;
    pooled[e] = pmax[(((size_t)0 * 8 + nt) * 64 + ln) * 16 + r];
    pooled[2 * E_ + e] = pmax[(((size_t)1 * 8 + nt) * 64 + ln) * 16 + r];
    __syncthreads();

    // FC: out[b][l] = fc_b[l] + pooled . fc_w[l]
    int l = e & 15, seg = e >> 4;  // 16 segments of 48
    float s = 0.0f;
    const float* wrow = fc_w + (size_t)l * (3 * E_) + seg * 48;
    const float* pp = pooled + seg * 48;
#pragma unroll 8
    for (int j = 0; j < 48; ++j) s += pp[j] * wrow[j];
    partial[l][seg] = s;
    __syncthreads();
    if (e < NLAB) {
        float acc = fc_b[e];
#pragma unroll
        for (int k = 0; k < 16; ++k) acc += partial[e][k];
        out[b * NLAB + e] = acc;
    }
}

extern "C" void kernel_launch(void* const* d_in, const int* in_sizes, int n_in,
                              void* d_out, int out_size, void* d_ws, size_t ws_size,
                              hipStream_t stream) {
    (void)in_sizes; (void)n_in; (void)out_size;
    const int* inputs = (const int*)d_in[0];
    const float* emb = (const float*)d_in[1];
    const float* Wl = (const float*)d_in[2];
    const float* Wsl = (const float*)d_in[3];
    const float* Wr = (const float*)d_in[4];
    const float* Wsr = (const float*)d_in[5];
    const float* e0p = (const float*)d_in[6];
    const float* e0f = (const float*)d_in[7];
    const float* fcw = (const float*)d_in[8];
    const float* fcb = (const float*)d_in[9];
    float* out = (float*)d_out;

    const size_t z_bytes = (size_t)2 * T_ * 8 * 64 * 16 * 4;       // 32 MB
    const size_t w_bytes = (size_t)2 * T_ * 8 * 16 * 64 * 8 * 2;   // 134 MB
    const size_t pm_bytes = (size_t)2 * 8 * 64 * 16 * 4;           // 64 KB
    char* ws = (char*)d_ws;

    if (ws_size >= z_bytes + w_bytes + pm_bytes) {
        float* z_frag = (float*)ws;
        unsigned short* wfrag = (unsigned short*)(ws + z_bytes);
        float* pmax = (float*)(ws + z_bytes + w_bytes);
        zcompute_kernel<<<1024, 512, 0, stream>>>(inputs, emb, Wsl, Wsr, e0p, e0f, z_frag);
        wpack_kernel<<<1024, 512, 0, stream>>>(Wl, Wr, wfrag);
        chain_kernel<0><<<2, 512, 0, stream>>>(inputs, emb, Wl, Wsl, Wr, Wsr, e0p, e0f,
                                               wfrag, z_frag, pmax);
        finalize_kernel<<<32, 256, 0, stream>>>(inputs, emb, pmax, fcw, fcb, out);
    } else {
        float* pmax = (float*)ws;
        chain_kernel<1><<<2, 512, 0, stream>>>(inputs, emb, Wl, Wsl, Wr, Wsr, e0p, e0f,
                                               nullptr, nullptr, pmax);
        finalize_kernel<<<32, 256, 0, stream>>>(inputs, emb, pmax, fcw, fcb, out);
    }
}